// Round 1
// baseline (319.457 us; speedup 1.0000x reference)
//
#include <hip/hip_runtime.h>
#include <math.h>

#define S_LEN 2048
#define D_DIM 64
#define NBH   32          // B*H = 2*16
#define TINV  0.125f      // 1/temperature

typedef float f32x4  __attribute__((ext_vector_type(4)));
typedef short s16x8  __attribute__((ext_vector_type(8)));
typedef short s16x4  __attribute__((ext_vector_type(4)));
typedef __bf16 bf16x8 __attribute__((ext_vector_type(8)));

__device__ __forceinline__ short f2bf(float f) {
  union { float f; unsigned u; } x; x.f = f;
  unsigned r = x.u + 0x7fffu + ((x.u >> 16) & 1u);
  return (short)(r >> 16);
}

__device__ __forceinline__ f32x4 mfma16(s16x8 a, s16x8 b, f32x4 c) {
  return __builtin_amdgcn_mfma_f32_16x16x32_bf16(
      __builtin_bit_cast(bf16x8, a), __builtin_bit_cast(bf16x8, b), c, 0, 0, 0);
}

// ---------------------------------------------------------------------------
// Kernel B: per (bh, 64-row q tile):
//   loop1: S = Q K^T (bf16 MFMA), p = exp(s/T) (masked), rowsum l, O += P V
//   write OT[bh][c][s] = (O/l) bf16 to ws; qt==0 blocks also write vT bf16
//   loop2: recompute S, write attn = p / l (fp32) to d_out
// ---------------------------------------------------------------------------
__global__ __launch_bounds__(256) void attn_fwd(
    const float* __restrict__ q, const float* __restrict__ k,
    const float* __restrict__ v, const int* __restrict__ mask,
    float* __restrict__ attn_out, short* __restrict__ OT,
    short* __restrict__ vT)
{
  __shared__ short Kl[64][72];      // K tile  [t][d], padded
  __shared__ short Vt[64][72];      // V tile transposed [d][t]
  __shared__ short Pl[4][16][72];   // per-wave P tile [row][t]

  const int bid = blockIdx.x;             // 0..1023
  // XCD-aware swizzle: each of 8 XCDs owns 4 consecutive bh values
  const int xcd   = bid & 7;
  const int chunk = bid >> 3;             // 0..127
  const int bh = xcd * 4 + (chunk >> 5);  // 0..31
  const int qt = chunk & 31;              // q tile index
  const int b  = bh >> 4;                 // batch (H=16)

  const int tid  = threadIdx.x;
  const int wave = tid >> 6;
  const int lane = tid & 63;
  const int lr   = lane & 15;             // lane row/col within frag
  const int lg   = lane >> 4;             // lane group 0..3

  const int r0   = qt * 64;
  const int wrow = r0 + wave * 16;        // this wave's 16-row base

  // --- Q fragments (rows wrow+lr, d = kk*32 + lg*8 + j) ---
  s16x8 aq[2];
  {
    const float* qp = q + ((size_t)(bh * S_LEN + wrow + lr)) * D_DIM + lg * 8;
    #pragma unroll
    for (int kk = 0; kk < 2; ++kk) {
      s16x8 f;
      #pragma unroll
      for (int j = 0; j < 8; ++j) f[j] = f2bf(qp[kk * 32 + j]);
      aq[kk] = f;
    }
  }

  f32x4 oacc[4];
  #pragma unroll
  for (int n = 0; n < 4; ++n) oacc[n] = (f32x4){0.f, 0.f, 0.f, 0.f};
  float rs[4] = {0.f, 0.f, 0.f, 0.f};

  const int st  = tid >> 2;          // staging row 0..63
  const int sd0 = (tid & 3) * 16;    // staging col base 0,16,32,48

  // ---------------- loop 1 ----------------
  for (int kt = 0; kt < 32; ++kt) {
    // stage K tile [t][d] and V tile transposed [d][t]
    {
      const float* kp = k + ((size_t)(bh * S_LEN + kt * 64 + st)) * D_DIM + sd0;
      const float* vp = v + ((size_t)(bh * S_LEN + kt * 64 + st)) * D_DIM + sd0;
      s16x8 k0, k1;
      #pragma unroll
      for (int j = 0; j < 8; ++j) { k0[j] = f2bf(kp[j]); k1[j] = f2bf(kp[8 + j]); }
      *(s16x8*)&Kl[st][sd0]     = k0;
      *(s16x8*)&Kl[st][sd0 + 8] = k1;
      #pragma unroll
      for (int j = 0; j < 16; ++j) Vt[sd0 + j][st] = f2bf(vp[j]);
    }
    __syncthreads();

    // one q-tile block per bh exports V^T bf16 for the final small GEMM
    if (qt == 0) {
      s16x8 a0 = *(s16x8*)&Vt[st][sd0];
      s16x8 a1 = *(s16x8*)&Vt[st][sd0 + 8];
      short* dst = vT + (size_t)(bh * 64 + st) * S_LEN + kt * 64 + sd0;
      *(s16x8*)dst       = a0;
      *(s16x8*)(dst + 8) = a1;
    }

    // S = Q K^T  (per wave: 16 rows x 64 cols)
    f32x4 sacc[4];
    #pragma unroll
    for (int n = 0; n < 4; ++n) {
      sacc[n] = (f32x4){0.f, 0.f, 0.f, 0.f};
      #pragma unroll
      for (int kk = 0; kk < 2; ++kk) {
        s16x8 bk = *(const s16x8*)&Kl[n * 16 + lr][kk * 32 + lg * 8];
        sacc[n] = mfma16(aq[kk], bk, sacc[n]);
      }
    }

    // mask + exp, rowsum accumulate, stash P (bf16) in wave-private LDS
    #pragma unroll
    for (int n = 0; n < 4; ++n) {
      const int t  = kt * 64 + n * 16 + lr;
      const int mv = mask[b * S_LEN + t];
      #pragma unroll
      for (int reg = 0; reg < 4; ++reg) {
        float p = mv ? __expf(sacc[n][reg] * TINV) : 0.f;
        rs[reg] += p;
        Pl[wave][lg * 4 + reg][n * 16 + lr] = f2bf(p);
      }
    }

    // O += P V
    #pragma unroll
    for (int kk = 0; kk < 2; ++kk) {
      s16x8 ap = *(const s16x8*)&Pl[wave][lr][kk * 32 + lg * 8];
      #pragma unroll
      for (int n = 0; n < 4; ++n) {
        s16x8 bv = *(const s16x8*)&Vt[n * 16 + lr][kk * 32 + lg * 8];
        oacc[n] = mfma16(ap, bv, oacc[n]);
      }
    }
    __syncthreads();
  }

  // --- rowsum reduce across the 16 lanes holding each row ---
  float rinv[4];
  #pragma unroll
  for (int reg = 0; reg < 4; ++reg) {
    float s = rs[reg];
    s += __shfl_xor(s, 1, 64);
    s += __shfl_xor(s, 2, 64);
    s += __shfl_xor(s, 4, 64);
    s += __shfl_xor(s, 8, 64);
    rinv[reg] = 1.0f / s;
  }

  // --- write OT[bh][c][s] = (O/l) bf16; acc row (=s) is contiguous per reg ---
  #pragma unroll
  for (int n = 0; n < 4; ++n) {
    s16x4 ov;
    #pragma unroll
    for (int reg = 0; reg < 4; ++reg) ov[reg] = f2bf(oacc[n][reg] * rinv[reg]);
    short* dst = OT + (size_t)(bh * 64 + n * 16 + lr) * S_LEN + wrow + lg * 4;
    *(s16x4*)dst = ov;
  }

  // ---------------- loop 2: stream normalized attn to HBM ----------------
  float* ap_out = attn_out + (size_t)bh * S_LEN * S_LEN;
  for (int kt = 0; kt < 32; ++kt) {
    {
      const float* kp = k + ((size_t)(bh * S_LEN + kt * 64 + st)) * D_DIM + sd0;
      s16x8 k0, k1;
      #pragma unroll
      for (int j = 0; j < 8; ++j) { k0[j] = f2bf(kp[j]); k1[j] = f2bf(kp[8 + j]); }
      *(s16x8*)&Kl[st][sd0]     = k0;
      *(s16x8*)&Kl[st][sd0 + 8] = k1;
    }
    __syncthreads();

    f32x4 sacc[4];
    #pragma unroll
    for (int n = 0; n < 4; ++n) {
      sacc[n] = (f32x4){0.f, 0.f, 0.f, 0.f};
      #pragma unroll
      for (int kk = 0; kk < 2; ++kk) {
        s16x8 bk = *(const s16x8*)&Kl[n * 16 + lr][kk * 32 + lg * 8];
        sacc[n] = mfma16(aq[kk], bk, sacc[n]);
      }
    }

    #pragma unroll
    for (int n = 0; n < 4; ++n) {
      const int t  = kt * 64 + n * 16 + lr;
      const int mv = mask[b * S_LEN + t];
      #pragma unroll
      for (int reg = 0; reg < 4; ++reg) {
        float pv = mv ? __expf(sacc[n][reg] * TINV) * rinv[reg] : 0.f;
        ap_out[(size_t)(wrow + lg * 4 + reg) * S_LEN + t] = pv;
      }
    }
    __syncthreads();
  }
}

// ---------------------------------------------------------------------------
// Kernel C: out[bh][d][c] = sum_s vT[d][s] * O[s][c]   (read O as OT[c][s])
// ---------------------------------------------------------------------------
__global__ __launch_bounds__(256) void vo_gemm(
    const short* __restrict__ vT, const short* __restrict__ OT,
    float* __restrict__ out)
{
  const int bh   = blockIdx.x;
  const int tid  = threadIdx.x;
  const int wave = tid >> 6;
  const int lane = tid & 63;
  const int lr   = lane & 15;
  const int lg   = lane >> 4;

  const short* vb = vT + (size_t)(bh * 64) * S_LEN;
  const short* ob = OT + (size_t)(bh * 64) * S_LEN;

  f32x4 acc[4];
  #pragma unroll
  for (int n = 0; n < 4; ++n) acc[n] = (f32x4){0.f, 0.f, 0.f, 0.f};

  for (int s = 0; s < S_LEN; s += 32) {
    s16x8 a = *(const s16x8*)&vb[(size_t)(wave * 16 + lr) * S_LEN + s + lg * 8];
    #pragma unroll
    for (int n = 0; n < 4; ++n) {
      s16x8 bo = *(const s16x8*)&ob[(size_t)(n * 16 + lr) * S_LEN + s + lg * 8];
      acc[n] = mfma16(a, bo, acc[n]);
    }
  }

  #pragma unroll
  for (int n = 0; n < 4; ++n) {
    #pragma unroll
    for (int reg = 0; reg < 4; ++reg) {
      const int d = wave * 16 + lg * 4 + reg;
      const int c = n * 16 + lr;
      out[(size_t)(bh * 64 + d) * 64 + c] = acc[n][reg];
    }
  }
}

extern "C" void kernel_launch(void* const* d_in, const int* in_sizes, int n_in,
                              void* d_out, int out_size, void* d_ws, size_t ws_size,
                              hipStream_t stream) {
  (void)in_sizes; (void)n_in; (void)out_size; (void)ws_size;
  const float* q    = (const float*)d_in[0];
  const float* k    = (const float*)d_in[1];
  const float* v    = (const float*)d_in[2];
  const int*   mask = (const int*)d_in[3];

  float* out  = (float*)d_out;
  float* attn = out + (size_t)NBH * 64 * 64;     // attn follows out in d_out

  short* OT = (short*)d_ws;                                  // 8 MiB bf16
  short* vT = (short*)d_ws + (size_t)NBH * 64 * S_LEN;       // 8 MiB bf16

  attn_fwd<<<dim3(1024), dim3(256), 0, stream>>>(q, k, v, mask, attn, OT, vT);
  vo_gemm<<<dim3(NBH), dim3(256), 0, stream>>>(vT, OT, out);
}

// Round 2
// 301.825 us; speedup vs baseline: 1.0584x; 1.0584x over previous
//
#include <hip/hip_runtime.h>
#include <math.h>

#define S_LEN 2048
#define D_DIM 64
#define NBH   32          // B*H = 2*16
#define TINV  0.125f      // 1/temperature

typedef float  f32x4  __attribute__((ext_vector_type(4)));
typedef short  s16x4  __attribute__((ext_vector_type(4)));
typedef short  s16x8  __attribute__((ext_vector_type(8)));
typedef __bf16 bf16x8 __attribute__((ext_vector_type(8)));

__device__ __forceinline__ short bfc(float f) {
  return __builtin_bit_cast(short, (__bf16)f);   // RNE, compiler packs pairs via v_cvt_pk_bf16_f32
}

__device__ __forceinline__ f32x4 mfma16(s16x8 a, s16x8 b, f32x4 c) {
  return __builtin_amdgcn_mfma_f32_16x16x32_bf16(
      __builtin_bit_cast(bf16x8, a), __builtin_bit_cast(bf16x8, b), c, 0, 0, 0);
}

// ---------------------------------------------------------------------------
// attn_fwd: per (bh, 64-row q tile)
//   loop1: S^T = K Q^T (swapped MFMA), p = exp(s/T) masked, rowsum, O += P V
//   loop2: recompute S^T, write attn = p/l as float4 nontemporal stores
// ---------------------------------------------------------------------------
__global__ __launch_bounds__(256, 4) void attn_fwd(
    const float* __restrict__ q, const float* __restrict__ k,
    const float* __restrict__ v, const int* __restrict__ mask,
    float* __restrict__ attn_out, short* __restrict__ OT,
    short* __restrict__ vT)
{
  __shared__ short Kl[64][72];      // K tile [t][d]
  __shared__ short Vt[64][72];      // V tile transposed [d][t]
  __shared__ short Pl[4][16][72];   // per-wave P tile [q][t]

  const int bid   = blockIdx.x;
  const int xcd   = bid & 7;
  const int chunk = bid >> 3;
  const int bh    = xcd * 4 + (chunk >> 5);
  const int qt    = chunk & 31;
  const int b     = bh >> 4;

  const int tid  = threadIdx.x;
  const int wave = tid >> 6;
  const int lane = tid & 63;
  const int lr   = lane & 15;
  const int lg   = lane >> 4;
  const int wrow = qt * 64 + wave * 16;

  // --- Q fragments: A/B-frag elem (lane lr row, k = kk*32 + lg*8 + j) ---
  s16x8 aq[2];
  {
    const float* qp = q + ((size_t)(bh * S_LEN + wrow + lr)) * D_DIM + lg * 8;
    #pragma unroll
    for (int kk = 0; kk < 2; ++kk) {
      s16x8 f;
      #pragma unroll
      for (int j = 0; j < 8; ++j) f[j] = bfc(qp[kk * 32 + j]);
      aq[kk] = f;
    }
  }

  f32x4 oacc[4];
  #pragma unroll
  for (int n = 0; n < 4; ++n) oacc[n] = (f32x4){0.f, 0.f, 0.f, 0.f};
  float rs = 0.f;

  // staging index maps
  const int st  = tid >> 2;          // K row 0..63
  const int sd0 = (tid & 3) * 16;    // K col base
  const int vt0 = (tid & 15) * 4;    // V t-block base
  const int vd0 = (tid >> 4) * 4;    // V d-block base

  const float* kbase = k + (size_t)bh * S_LEN * D_DIM;
  const float* vbase = v + (size_t)bh * S_LEN * D_DIM;

  f32x4 kr[4], vr[4];
  #pragma unroll
  for (int i = 0; i < 4; ++i) {
    kr[i] = *(const f32x4*)(kbase + (size_t)st * D_DIM + sd0 + i * 4);
    vr[i] = *(const f32x4*)(vbase + (size_t)(vt0 + i) * D_DIM + vd0);
  }

  // ---------------- loop 1 ----------------
  for (int kt = 0; kt < 32; ++kt) {
    __syncthreads();   // prior iteration's LDS reads complete

    // K tile write (row-major, vectorized)
    {
      s16x8 k0, k1;
      #pragma unroll
      for (int j = 0; j < 4; ++j) {
        k0[j] = bfc(kr[0][j]); k0[4 + j] = bfc(kr[1][j]);
        k1[j] = bfc(kr[2][j]); k1[4 + j] = bfc(kr[3][j]);
      }
      *(s16x8*)&Kl[st][sd0]     = k0;
      *(s16x8*)&Kl[st][sd0 + 8] = k1;
    }
    // V 4x4 register transpose -> b64 writes
    #pragma unroll
    for (int j = 0; j < 4; ++j) {
      s16x4 pk;
      pk[0] = bfc(vr[0][j]); pk[1] = bfc(vr[1][j]);
      pk[2] = bfc(vr[2][j]); pk[3] = bfc(vr[3][j]);
      *(s16x4*)&Vt[vd0 + j][vt0] = pk;
    }

    // prefetch next tile into regs (hides L2 latency under compute)
    if (kt + 1 < 32) {
      #pragma unroll
      for (int i = 0; i < 4; ++i) {
        kr[i] = *(const f32x4*)(kbase + (size_t)((kt + 1) * 64 + st) * D_DIM + sd0 + i * 4);
        vr[i] = *(const f32x4*)(vbase + (size_t)((kt + 1) * 64 + vt0 + i) * D_DIM + vd0);
      }
    }

    // mask bits for this kt tile: bit i = mask[kt*64+i] != 0
    const unsigned long long mbits = __ballot(mask[b * S_LEN + kt * 64 + lane] != 0);

    __syncthreads();

    // export V^T bf16 once per bh (for the final small GEMM)
    if (qt == 0) {
      s16x8 a0 = *(s16x8*)&Vt[st][sd0];
      s16x8 a1 = *(s16x8*)&Vt[st][sd0 + 8];
      short* dst = vT + (size_t)(bh * 64 + st) * S_LEN + kt * 64 + sd0;
      *(s16x8*)dst       = a0;
      *(s16x8*)(dst + 8) = a1;
    }

    // S^T = K Q^T : lane holds q=lr, t = n*16 + lg*4 + reg
    #pragma unroll
    for (int n = 0; n < 4; ++n) {
      f32x4 sacc = (f32x4){0.f, 0.f, 0.f, 0.f};
      #pragma unroll
      for (int kk = 0; kk < 2; ++kk) {
        s16x8 bk = *(const s16x8*)&Kl[n * 16 + lr][kk * 32 + lg * 8];
        sacc = mfma16(bk, aq[kk], sacc);
      }
      const unsigned nib = (unsigned)(mbits >> (n * 16 + lg * 4)) & 0xFu;
      s16x4 pk;
      #pragma unroll
      for (int reg = 0; reg < 4; ++reg) {
        float e = __expf(sacc[reg] * TINV);
        float p = (nib & (1u << reg)) ? e : 0.f;
        rs += p;
        pk[reg] = bfc(p);
      }
      *(s16x4*)&Pl[wave][lr][n * 16 + lg * 4] = pk;   // P[q=lr][t] b64 write
    }

    // O += P V  (A = P rows q, B = V^T rows d)
    #pragma unroll
    for (int kk = 0; kk < 2; ++kk) {
      s16x8 ap = *(const s16x8*)&Pl[wave][lr][kk * 32 + lg * 8];
      #pragma unroll
      for (int n = 0; n < 4; ++n) {
        s16x8 bv = *(const s16x8*)&Vt[n * 16 + lr][kk * 32 + lg * 8];
        oacc[n] = mfma16(ap, bv, oacc[n]);
      }
    }
  }

  // rowsum reduce: lanes {lr, lr+16, lr+32, lr+48} hold partials of q-row lr
  rs += __shfl_xor(rs, 16, 64);
  rs += __shfl_xor(rs, 32, 64);
  const float rinv = 1.0f / rs;          // for q-row = lr

  // rinv for OT's reg layout (q = lg*4 + reg): pull from lane lg*4+reg
  float rinvO[4];
  #pragma unroll
  for (int reg = 0; reg < 4; ++reg)
    rinvO[reg] = __shfl(rinv, lg * 4 + reg, 64);

  // OT[bh][d][s] = (O/l) bf16 ; oacc[n]: q = lg*4+reg, d = n*16+lr
  #pragma unroll
  for (int n = 0; n < 4; ++n) {
    s16x4 ov;
    #pragma unroll
    for (int reg = 0; reg < 4; ++reg) ov[reg] = bfc(oacc[n][reg] * rinvO[reg]);
    short* dst = OT + (size_t)(bh * 64 + n * 16 + lr) * S_LEN + wrow + lg * 4;
    *(s16x4*)dst = ov;
  }

  // ---------------- loop 2: stream normalized attn ----------------
  float* ap_out = attn_out + (size_t)bh * S_LEN * S_LEN + (size_t)(wrow + lr) * S_LEN;

  #pragma unroll
  for (int i = 0; i < 4; ++i)
    kr[i] = *(const f32x4*)(kbase + (size_t)st * D_DIM + sd0 + i * 4);

  for (int kt = 0; kt < 32; ++kt) {
    __syncthreads();
    {
      s16x8 k0, k1;
      #pragma unroll
      for (int j = 0; j < 4; ++j) {
        k0[j] = bfc(kr[0][j]); k0[4 + j] = bfc(kr[1][j]);
        k1[j] = bfc(kr[2][j]); k1[4 + j] = bfc(kr[3][j]);
      }
      *(s16x8*)&Kl[st][sd0]     = k0;
      *(s16x8*)&Kl[st][sd0 + 8] = k1;
    }
    if (kt + 1 < 32) {
      #pragma unroll
      for (int i = 0; i < 4; ++i)
        kr[i] = *(const f32x4*)(kbase + (size_t)((kt + 1) * 64 + st) * D_DIM + sd0 + i * 4);
    }
    const unsigned long long mbits = __ballot(mask[b * S_LEN + kt * 64 + lane] != 0);
    __syncthreads();

    #pragma unroll
    for (int n = 0; n < 4; ++n) {
      f32x4 sacc = (f32x4){0.f, 0.f, 0.f, 0.f};
      #pragma unroll
      for (int kk = 0; kk < 2; ++kk) {
        s16x8 bk = *(const s16x8*)&Kl[n * 16 + lr][kk * 32 + lg * 8];
        sacc = mfma16(bk, aq[kk], sacc);
      }
      const unsigned nib = (unsigned)(mbits >> (n * 16 + lg * 4)) & 0xFu;
      f32x4 pv;
      #pragma unroll
      for (int reg = 0; reg < 4; ++reg) {
        float e = __expf(sacc[reg] * TINV);
        pv[reg] = (nib & (1u << reg)) ? e * rinv : 0.f;
      }
      __builtin_nontemporal_store(pv, (f32x4*)(ap_out + kt * 64 + n * 16 + lg * 4));
    }
  }
}

// ---------------------------------------------------------------------------
// vo_gemm: out[bh][d][c] = sum_s vT[d][s] * OT[c][s]
// ---------------------------------------------------------------------------
__global__ __launch_bounds__(256) void vo_gemm(
    const short* __restrict__ vT, const short* __restrict__ OT,
    float* __restrict__ out)
{
  const int bh   = blockIdx.x;
  const int tid  = threadIdx.x;
  const int wave = tid >> 6;
  const int lane = tid & 63;
  const int lr   = lane & 15;
  const int lg   = lane >> 4;

  const short* vb = vT + (size_t)(bh * 64) * S_LEN;
  const short* ob = OT + (size_t)(bh * 64) * S_LEN;

  f32x4 acc[4];
  #pragma unroll
  for (int n = 0; n < 4; ++n) acc[n] = (f32x4){0.f, 0.f, 0.f, 0.f};

  for (int s = 0; s < S_LEN; s += 32) {
    s16x8 a = *(const s16x8*)&vb[(size_t)(wave * 16 + lr) * S_LEN + s + lg * 8];
    #pragma unroll
    for (int n = 0; n < 4; ++n) {
      s16x8 bo = *(const s16x8*)&ob[(size_t)(n * 16 + lr) * S_LEN + s + lg * 8];
      acc[n] = mfma16(a, bo, acc[n]);
    }
  }

  #pragma unroll
  for (int n = 0; n < 4; ++n) {
    #pragma unroll
    for (int reg = 0; reg < 4; ++reg) {
      const int d = wave * 16 + lg * 4 + reg;
      const int c = n * 16 + lr;
      out[(size_t)(bh * 64 + d) * 64 + c] = acc[n][reg];
    }
  }
}

extern "C" void kernel_launch(void* const* d_in, const int* in_sizes, int n_in,
                              void* d_out, int out_size, void* d_ws, size_t ws_size,
                              hipStream_t stream) {
  (void)in_sizes; (void)n_in; (void)out_size; (void)ws_size;
  const float* q    = (const float*)d_in[0];
  const float* k    = (const float*)d_in[1];
  const float* v    = (const float*)d_in[2];
  const int*   mask = (const int*)d_in[3];

  float* out  = (float*)d_out;
  float* attn = out + (size_t)NBH * 64 * 64;

  short* OT = (short*)d_ws;
  short* vT = (short*)d_ws + (size_t)NBH * 64 * S_LEN;

  attn_fwd<<<dim3(1024), dim3(256), 0, stream>>>(q, k, v, mask, attn, OT, vT);
  vo_gemm<<<dim3(NBH), dim3(256), 0, stream>>>(vT, OT, out);
}